// Round 6
// baseline (406.198 us; speedup 1.0000x reference)
//
#include <hip/hip_runtime.h>
#include <math.h>

#define S      512
#define BATCH  32
#define NGRP   256           // diagonal groups of 4: p in [0,1023) -> p>>2 in [0,256)
#define LDSP   68
#define INFF   __builtin_huge_valf()

// wave-wide shift-up-by-1 via DPP wave_shr:1 (VALU, no DS pipe).
// lane i gets src[i-1]; lane 0 gets old's lane-0 value (bound_ctrl=false).
__device__ __forceinline__ float dpp_shr1(float src, float old) {
    return __int_as_float(__builtin_amdgcn_update_dpp(
        __float_as_int(old), __float_as_int(src), 0x138, 0xf, 0xf, false));
}

// full-wave rotate: lane i gets src[(i-1)&63] (lane 0 <- lane 63).
__device__ __forceinline__ float dpp_ror1(float src) {
    return __int_as_float(__builtin_amdgcn_update_dpp(
        0, __float_as_int(src), 0x13C, 0xf, 0xf, false));
}

__device__ __forceinline__ float lane_bcast(float v, int l) {
    return __int_as_float(__builtin_amdgcn_readlane(__float_as_int(v), l));
}

// ---------------------------------------------------------------------------
// Kernel 1: D[b,i,j] = |x_i|^2 + |y_j|^2 - 2<x_i,y_j>, stored in 4-wide
// diagonal groups:  ws[b][p>>2][i][p&3]  with p = i + j.  (unchanged)
// ---------------------------------------------------------------------------
__global__ __launch_bounds__(256) void pairdist_kernel(
    const float* __restrict__ X, const float* __restrict__ Y,
    float* __restrict__ Dd)
{
    const int b   = blockIdx.z;
    const int i0  = blockIdx.y * 64;
    const int j0  = blockIdx.x * 64;
    const int tid = threadIdx.x;

    __shared__ float smem[64 * LDSP * 2];
    __shared__ float x2s[64], y2s[64];
    float* XsT = smem;
    float* YsT = smem + 64 * LDSP;

    const float* Xb = X + ((size_t)b * S + i0) * 64;
    const float* Yb = Y + ((size_t)b * S + j0) * 64;

#pragma unroll
    for (int c = 0; c < 4; ++c) {
        int idx = c * 1024 + tid * 4;
        int row = idx >> 6;
        int k   = idx & 63;
        float4 vx = *(const float4*)(Xb + (size_t)row * 64 + k);
        float4 vy = *(const float4*)(Yb + (size_t)row * 64 + k);
        XsT[(k + 0) * LDSP + row] = vx.x; XsT[(k + 1) * LDSP + row] = vx.y;
        XsT[(k + 2) * LDSP + row] = vx.z; XsT[(k + 3) * LDSP + row] = vx.w;
        YsT[(k + 0) * LDSP + row] = vy.x; YsT[(k + 1) * LDSP + row] = vy.y;
        YsT[(k + 2) * LDSP + row] = vy.z; YsT[(k + 3) * LDSP + row] = vy.w;
    }
    __syncthreads();

    if (tid < 64) {
        float s = 0.f;
#pragma unroll 8
        for (int k = 0; k < 64; ++k) { float v = XsT[k * LDSP + tid]; s = fmaf(v, v, s); }
        x2s[tid] = s;
    } else if (tid < 128) {
        int r = tid - 64;
        float s = 0.f;
#pragma unroll 8
        for (int k = 0; k < 64; ++k) { float v = YsT[k * LDSP + r]; s = fmaf(v, v, s); }
        y2s[r] = s;
    }
    __syncthreads();

    const int tx = tid & 15;
    const int ty = tid >> 4;
    float acc[4][4] = {};
#pragma unroll 4
    for (int k = 0; k < 64; ++k) {
        float4 a  = *(const float4*)&XsT[k * LDSP + ty * 4];
        float4 bb = *(const float4*)&YsT[k * LDSP + tx * 4];
        float av[4] = {a.x, a.y, a.z, a.w};
        float bv[4] = {bb.x, bb.y, bb.z, bb.w};
#pragma unroll
        for (int r = 0; r < 4; ++r)
#pragma unroll
            for (int c = 0; c < 4; ++c)
                acc[r][c] = fmaf(av[r], bv[c], acc[r][c]);
    }

    float xr[4], yc[4];
#pragma unroll
    for (int r = 0; r < 4; ++r) xr[r] = x2s[ty * 4 + r];
#pragma unroll
    for (int c = 0; c < 4; ++c) yc[c] = y2s[tx * 4 + c];

    float vout[4][4];
#pragma unroll
    for (int r = 0; r < 4; ++r)
#pragma unroll
        for (int c = 0; c < 4; ++c)
            vout[r][c] = xr[r] + yc[c] - 2.0f * acc[r][c];

    __syncthreads();

    float* diag = smem;
#pragma unroll
    for (int r = 0; r < 4; ++r) {
        int il = ty * 4 + r;
#pragma unroll
        for (int cc = 0; cc < 4; ++cc) {
            int c   = (cc + tx + ty) & 3;
            float v = vout[r][0];
            v = (c == 1) ? vout[r][1] : v;
            v = (c == 2) ? vout[r][2] : v;
            v = (c == 3) ? vout[r][3] : v;
            int jl = tx * 4 + c;
            diag[il * 128 + jl] = v;
        }
    }
    __syncthreads();

    const int w     = tid >> 6;
    const int il    = tid & 63;
    const int gbase = (i0 + j0) >> 2;
    float* dstB = Dd + (size_t)b * (NGRP * S * 4);
#pragma unroll
    for (int t = 0; t < 8; ++t) {
        int gl   = w + 4 * t;
        int joff = 4 * gl - il;
        float c0 = diag[il * 127 + 4 * gl + 0];
        float c1 = diag[il * 127 + 4 * gl + 1];
        float c2 = diag[il * 127 + 4 * gl + 2];
        float c3 = diag[il * 127 + 4 * gl + 3];
        size_t base = ((size_t)(gbase + gl) * S + (i0 + il)) * 4;
        if (joff >= 0 && joff <= 60) {
            float4 v; v.x = c0; v.y = c1; v.z = c2; v.w = c3;
            *(float4*)(dstB + base) = v;
        } else {
            if ((unsigned)(joff + 0) <= 63u) dstB[base + 0] = c0;
            if ((unsigned)(joff + 1) <= 63u) dstB[base + 1] = c1;
            if ((unsigned)(joff + 2) <= 63u) dstB[base + 2] = c2;
            if ((unsigned)(joff + 3) <= 63u) dstB[base + 3] = c3;
        }
    }
}

// ---------------------------------------------------------------------------
// Kernel 2 (v6): 16-wave, TWO batches per block -> 4 independent DP chains
// per SIMD (v5 measured latency-bound at 2 chains/SIMD: 159 cyc/cell,
// VALUBusy ~37% on active CUs).
// Waves 0-7 run batch 2*bx+0, waves 8-15 run batch 2*bx+1; within a batch
// the structure is exactly v5 (verified bit-exact): wave ww works strip
// 2*(ww&3)+(ww>>2), strip owns rows [64*strip, 64*strip+64), stagger 2
// super-steps, double-buffered reversed ring + extraS boundary handoff,
// E/O diagonal-parity register banks, window-0 predication, 23 super-steps.
// All correctness arguments carry over verbatim (the two batches share only
// the barrier). Per-cell FP expression identical to v1-v5 -> bit-exact.
// ---------------------------------------------------------------------------
__global__ __launch_bounds__(1024) void softdtw_dp_stag16(
    const float* __restrict__ Dd, float* __restrict__ out)
{
    const int bx    = blockIdx.x;
    const int tid   = threadIdx.x;
    const int w     = tid >> 6;          // 0..15
    const int wg    = w >> 3;            // batch slot 0/1
    const int ww    = w & 7;             // wave id within batch
    const int lane  = tid & 63;
    const int strip = 2 * (ww & 3) + (ww >> 2);   // SIMD-pairing permutation
    const int b     = 2 * bx + wg;

    __shared__ float ring[2][7][2][64];   // [wg] reversed boundary blocks
    __shared__ float extraS[2][7][2];     // [wg] previous block's last value

    const float4* __restrict__ Dbat =
        (const float4*)(Dd + (size_t)b * (NGRP * S * 4));

    const int  i0   = 64 * strip + lane;     // this lane's row
    const bool is63 = (lane == 63);

    float rE = INFF, rO = INFF;        // even-diag bank, odd-diag bank
    float up_prev = INFF, tshift = INFF, tacc = 0.0f, last_prev = INFF;
    float4 Q[4];
    int qg = 0;                        // group consumed by current GITER

    // one cell: PW = write bank (diag p-2 -> p), CU = other bank (diag p-1)
#define CELL1(PW, CU, qc, PRED, kk)                                      \
    {                                                                    \
        float up = dpp_shr1(CU, tshift);   /* lane0 <- stream(p-1) */    \
        tshift = dpp_ror1(tshift);                                       \
        float dd = up_prev, lf = CU;                                     \
        float mn = fminf(up, fminf(dd, lf));                             \
        float e  = __expf(mn - dd) + __expf(mn - up) + __expf(mn - lf);  \
        float val = (qc) + (mn - __logf(e));                             \
        if (PRED) val = (lane <= (kk)) ? val : PW;                       \
        PW = val;                                                        \
        tacc = dpp_ror1(is63 ? PW : tacc);                               \
        up_prev = up;                                                    \
    }

    // 4 steps = one D group (p0 = multiple of 4 -> parity E,O,E,O static)
#define GITER1(Qi, PRED, kk)                                             \
    {                                                                    \
        float4 q = Q[Qi];                                                \
        int gq = qg + 4; gq = (gq > 255) ? 255 : gq;                     \
        Q[Qi] = *(Dbat + (size_t)gq * S + i0);                           \
        qg += 1;                                                         \
        CELL1(rE, rO, q.x, PRED, (kk) + 0)                               \
        CELL1(rO, rE, q.y, PRED, (kk) + 1)                               \
        CELL1(rE, rO, q.z, PRED, (kk) + 2)                               \
        CELL1(rO, rE, q.w, PRED, (kk) + 3)                               \
    }

    for (int n = 0; n < 23; ++n) {
        const int na = n - 2 * strip;
        if (0 <= na && na < 9) {
            if (na == 0) {                 // strip-run start: seed + queue fill
                up_prev = (strip == 0) ? 0.0f : INFF;   // corner / INF wall
                qg = 16 * strip;
#pragma unroll
                for (int i = 0; i < 4; ++i)
                    Q[i] = *(Dbat + (size_t)(qg + i) * S + i0);
            }
            if (strip > 0) {               // load stream block for this window
                float t  = ring[wg][strip - 1][(n - 1) & 1][lane];
                float ex = extraS[wg][strip - 1][(n - 1) & 1];
                tshift = (lane == 0) ? ex : t;
            } else {
                tshift = INFF;             // R[-1][*] wall for strip 0
            }

            if (na == 0) {                 // predicated window (j >= 0 edge)
#pragma unroll
                for (int it = 0; it < 4; ++it) {
                    const int kk = 16 * it;
                    GITER1(0, true, kk)      GITER1(1, true, kk + 4)
                    GITER1(2, true, kk + 8)  GITER1(3, true, kk + 12)
                }
            } else {                       // hot loop
#pragma unroll 1
                for (int it = 0; it < 4; ++it) {
                    GITER1(0, false, 0) GITER1(1, false, 0)
                    GITER1(2, false, 0) GITER1(3, false, 0)
                }
            }

            if (strip < 7) {               // publish boundary block
                ring[wg][strip][n & 1][lane] = tacc;
                if (lane == 0) extraS[wg][strip][n & 1] = last_prev;
                last_prev = lane_bcast(tacc, 0);   // this window's last value
            }
        }
        __syncthreads();
    }
#undef GITER1
#undef CELL1

    // R[511][511]: strip 7, lane 63, diag 1022 (even bank); one per batch slot
    if (lane == 63 && strip == 7) out[b] = rE;
}

// ---------------------------------------------------------------------------
extern "C" void kernel_launch(void* const* d_in, const int* in_sizes, int n_in,
                              void* d_out, int out_size, void* d_ws, size_t ws_size,
                              hipStream_t stream)
{
    const float* X = (const float*)d_in[0];
    const float* Y = (const float*)d_in[1];
    float* out = (float*)d_out;
    float* Dd  = (float*)d_ws;   // 32 * 256*512*4 floats = 64 MiB

    dim3 g1(S / 64, S / 64, BATCH);
    pairdist_kernel<<<g1, 256, 0, stream>>>(X, Y, Dd);

    softdtw_dp_stag16<<<BATCH / 2, 1024, 0, stream>>>(Dd, out);
}

// Round 8
// 286.317 us; speedup vs baseline: 1.4187x; 1.4187x over previous
//
#include <hip/hip_runtime.h>
#include <math.h>

#define S      512
#define BATCH  32
#define NGRP   256           // diagonal groups of 4: p in [0,1023) -> p>>2 in [0,256)
#define LDSP   68
#define INFF   __builtin_huge_valf()

// wave-wide shift-up-by-1 via DPP wave_shr:1 (VALU, no DS pipe).
// lane i gets src[i-1]; lane 0 gets old's lane-0 value (bound_ctrl=false). [HW-verified]
__device__ __forceinline__ float dpp_shr1(float src, float old) {
    return __int_as_float(__builtin_amdgcn_update_dpp(
        __float_as_int(old), __float_as_int(src), 0x138, 0xf, 0xf, false));
}

// full-wave rotate DOWN: lane i gets src[(i+1)&63] (lane 63 <- lane 0).
// (0x134 = wave_rol:1; direction is the mirror of the HW-verified 0x13C wave_ror.)
__device__ __forceinline__ float dpp_rol1(float src) {
    return __int_as_float(__builtin_amdgcn_update_dpp(
        0, __float_as_int(src), 0x134, 0xf, 0xf, false));
}

// ---------------------------------------------------------------------------
// Kernel 1: D[b,i,j] = |x_i|^2 + |y_j|^2 - 2<x_i,y_j>, stored in 4-wide
// diagonal groups:  ws[b][p>>2][i][p&3]  with p = i + j.  (unchanged)
// ---------------------------------------------------------------------------
__global__ __launch_bounds__(256) void pairdist_kernel(
    const float* __restrict__ X, const float* __restrict__ Y,
    float* __restrict__ Dd)
{
    const int b   = blockIdx.z;
    const int i0  = blockIdx.y * 64;
    const int j0  = blockIdx.x * 64;
    const int tid = threadIdx.x;

    __shared__ float smem[64 * LDSP * 2];
    __shared__ float x2s[64], y2s[64];
    float* XsT = smem;
    float* YsT = smem + 64 * LDSP;

    const float* Xb = X + ((size_t)b * S + i0) * 64;
    const float* Yb = Y + ((size_t)b * S + j0) * 64;

#pragma unroll
    for (int c = 0; c < 4; ++c) {
        int idx = c * 1024 + tid * 4;
        int row = idx >> 6;
        int k   = idx & 63;
        float4 vx = *(const float4*)(Xb + (size_t)row * 64 + k);
        float4 vy = *(const float4*)(Yb + (size_t)row * 64 + k);
        XsT[(k + 0) * LDSP + row] = vx.x; XsT[(k + 1) * LDSP + row] = vx.y;
        XsT[(k + 2) * LDSP + row] = vx.z; XsT[(k + 3) * LDSP + row] = vx.w;
        YsT[(k + 0) * LDSP + row] = vy.x; YsT[(k + 1) * LDSP + row] = vy.y;
        YsT[(k + 2) * LDSP + row] = vy.z; YsT[(k + 3) * LDSP + row] = vy.w;
    }
    __syncthreads();

    if (tid < 64) {
        float s = 0.f;
#pragma unroll 8
        for (int k = 0; k < 64; ++k) { float v = XsT[k * LDSP + tid]; s = fmaf(v, v, s); }
        x2s[tid] = s;
    } else if (tid < 128) {
        int r = tid - 64;
        float s = 0.f;
#pragma unroll 8
        for (int k = 0; k < 64; ++k) { float v = YsT[k * LDSP + r]; s = fmaf(v, v, s); }
        y2s[r] = s;
    }
    __syncthreads();

    const int tx = tid & 15;
    const int ty = tid >> 4;
    float acc[4][4] = {};
#pragma unroll 4
    for (int k = 0; k < 64; ++k) {
        float4 a  = *(const float4*)&XsT[k * LDSP + ty * 4];
        float4 bb = *(const float4*)&YsT[k * LDSP + tx * 4];
        float av[4] = {a.x, a.y, a.z, a.w};
        float bv[4] = {bb.x, bb.y, bb.z, bb.w};
#pragma unroll
        for (int r = 0; r < 4; ++r)
#pragma unroll
            for (int c = 0; c < 4; ++c)
                acc[r][c] = fmaf(av[r], bv[c], acc[r][c]);
    }

    float xr[4], yc[4];
#pragma unroll
    for (int r = 0; r < 4; ++r) xr[r] = x2s[ty * 4 + r];
#pragma unroll
    for (int c = 0; c < 4; ++c) yc[c] = y2s[tx * 4 + c];

    float vout[4][4];
#pragma unroll
    for (int r = 0; r < 4; ++r)
#pragma unroll
        for (int c = 0; c < 4; ++c)
            vout[r][c] = xr[r] + yc[c] - 2.0f * acc[r][c];

    __syncthreads();

    float* diag = smem;
#pragma unroll
    for (int r = 0; r < 4; ++r) {
        int il = ty * 4 + r;
#pragma unroll
        for (int cc = 0; cc < 4; ++cc) {
            int c   = (cc + tx + ty) & 3;
            float v = vout[r][0];
            v = (c == 1) ? vout[r][1] : v;
            v = (c == 2) ? vout[r][2] : v;
            v = (c == 3) ? vout[r][3] : v;
            int jl = tx * 4 + c;
            diag[il * 128 + jl] = v;
        }
    }
    __syncthreads();

    const int w     = tid >> 6;
    const int il    = tid & 63;
    const int gbase = (i0 + j0) >> 2;
    float* dstB = Dd + (size_t)b * (NGRP * S * 4);
#pragma unroll
    for (int t = 0; t < 8; ++t) {
        int gl   = w + 4 * t;
        int joff = 4 * gl - il;
        float c0 = diag[il * 127 + 4 * gl + 0];
        float c1 = diag[il * 127 + 4 * gl + 1];
        float c2 = diag[il * 127 + 4 * gl + 2];
        float c3 = diag[il * 127 + 4 * gl + 3];
        size_t base = ((size_t)(gbase + gl) * S + (i0 + il)) * 4;
        if (joff >= 0 && joff <= 60) {
            float4 v; v.x = c0; v.y = c1; v.z = c2; v.w = c3;
            *(float4*)(dstB + base) = v;
        } else {
            if ((unsigned)(joff + 0) <= 63u) dstB[base + 0] = c0;
            if ((unsigned)(joff + 1) <= 63u) dstB[base + 1] = c1;
            if ((unsigned)(joff + 2) <= 63u) dstB[base + 2] = c2;
            if ((unsigned)(joff + 3) <= 63u) dstB[base + 3] = c3;
        }
    }
}

// ---------------------------------------------------------------------------
// Kernel 2 (v7): half-wave staggered soft-DTW DP — 16 strips x 32 rows,
// 8 waves, 4 independent chains per SIMD, 32 blocks (1 batch/block/CU).
// Wave pair sig = 2*(w&3)+(w>>2); half h=0 (lanes 0-31) = strip 2sig,
// h=1 (lanes 32-63) = strip 2sig+1. Lane row i = 32*strip + (lane&31).
// Strip t offset = 2t super-steps; window = 32 diagonals; 17 windows/strip;
// 47 super-steps total. One tshift register carries both halves' boundary
// streams (lane k = A(k), lane 32+k = B(k)), consumed at lanes 0/32
// (dpp_shr1 old-operand + one cndmask for lane 32) and advanced by one
// wave_rol:1/step. Bottom rows (lanes 31/63) collect via rol-then-blend
// into tacc (value k lands at lanes k / 32+k), published per window into a
// double-buffered LDS ring (64 slots + 2 prev-window extras). Odd strips
// consume their own wave's A-block (intra-wave); even strips consume the
// previous pair's B-block. Window-edge predication folds to single
// compares: head (lane<=k / lane<=32+k), tail (lane>k / lane>32+k).
// Per-cell FP expression and order identical to v1-v6 -> bit-exact.
// ---------------------------------------------------------------------------
__global__ __launch_bounds__(512) void softdtw_dp_hw(
    const float* __restrict__ Dd, float* __restrict__ out)
{
    const int b    = blockIdx.x;
    const int tid  = threadIdx.x;
    const int w    = tid >> 6;
    const int lane = tid & 63;
    const int ll   = lane & 31;                 // half-local lane
    const int h    = lane >> 5;                 // half id
    const int sig  = 2 * (w & 3) + (w >> 2);    // strip-pair; SIMD s hosts sig=2s,2s+1

    __shared__ float ringbuf[2][8][66];   // [parity][pair][0-63 block |64 exA |65 exB]

    const float4* __restrict__ Dbat =
        (const float4*)(Dd + (size_t)b * (NGRP * S * 4));

    const int  strip = 2 * sig + h;
    const int  row   = 32 * strip + ll;         // this lane's matrix row i
    const bool is32  = (lane == 32);
    const bool isbot = (ll == 31);              // lanes 31 and 63
    const bool wallA = (sig == 0) && (h == 0);  // strip 0: INF wall stream

    // consumer LDS addresses (per parity):
    //  h=0: producer pair sig-1, B-block: slot = ll? 31+ll : 65 (extraB)
    //  h=1: producer pair sig (own wave), A-block: slot = ll? ll-1 : 64 (extraA)
    const int sp   = h ? sig : (sig ? sig - 1 : 0);
    const int slot = (ll == 0) ? (h ? 64 : 65) : (h ? (ll - 1) : (31 + ll));
    const float* rd0 = &ringbuf[0][sp][slot];
    const float* rd1 = &ringbuf[1][sp][slot];

    float r = INFF, up_prev = INFF, tshift = INFF, tacc = INFF, eS = INFF;
    float4 Q[4];

    // one DP step; PRED is a statement using val/r/lane (or empty)
#define STEP(QC, PRED)                                                    \
    {                                                                     \
        float up = dpp_shr1(r, tshift);        /* lane0 <- tshift[0] */   \
        up = is32 ? tshift : up;               /* lane32 <- tshift[32] */ \
        tshift = dpp_rol1(tshift);                                        \
        float dd = up_prev, lf = r;                                       \
        float mn = fminf(up, fminf(dd, lf));                              \
        float e  = __expf(mn - dd) + __expf(mn - up) + __expf(mn - lf);   \
        float val = (QC) + (mn - __logf(e));                              \
        PRED                                                              \
        r = val;                                                          \
        float tr = dpp_rol1(tacc);             /* rotate, THEN insert */  \
        tacc = isbot ? r : tr;                                            \
        up_prev = up;                                                     \
    }

    // 4 steps = one D group; Qi compile-time (no scratch), M may be runtime
#define GIT(Qi, M, PRED)                                                  \
    {                                                                     \
        float4 q = Q[Qi];                                                 \
        int o = (M) + 4; o = (o > pfcap) ? pfcap : o;                     \
        Q[Qi] = wp[(size_t)o * S];                                        \
        const int kk = 4 * (M);                                           \
        STEP(q.x, PRED(kk + 0)) STEP(q.y, PRED(kk + 1))                   \
        STEP(q.z, PRED(kk + 2)) STEP(q.w, PRED(kk + 3))                   \
    }

#define WINBODY(PRED)                                                     \
    _Pragma("unroll 1")                                                   \
    for (int it = 0; it < 2; ++it) {                                      \
        const int mb = 4 * it;                                            \
        GIT(0, mb + 0, PRED) GIT(1, mb + 1, PRED)                         \
        GIT(2, mb + 2, PRED) GIT(3, mb + 3, PRED)                         \
    }

#define P_NONE(k)
#define P_AHEAD(k)  val = (lane <= (k)) ? val : r;       /* A head, B off  */
#define P_AON(k)    val = (lane <= 31) ? val : r;        /* A on,   B off  */
#define P_BHEAD(k)  val = (lane <= 32 + (k)) ? val : r;  /* A on,   B head */
#define P_ATAIL(k)  val = (lane > (k)) ? val : r;        /* A tail, B on   */
#define P_BON(k)    val = (lane > 31) ? val : r;         /* A off,  B on   */
#define P_BTAIL(k)  val = (lane > 32 + (k)) ? val : r;   /* A off,  B tail */

    for (int n = 0; n < 47; ++n) {
        const int naA = n - 4 * sig;           // wave-uniform
        if (0 <= naA && naA < 19) {
            // window base group: g = 16sig + 8h + 8*na_h = 8n - 16sig - 8h
            int g0 = 8 * n - 16 * sig - 8 * h;
            g0 = g0 < 0 ? 0 : (g0 > 248 ? 248 : g0);
            const float4* wp = Dbat + (size_t)g0 * S + row;
            const int pfcap = 255 - g0;

            // boundary stream for this window (published at super-step n-1)
            float tv = (n & 1) ? *rd0 : *rd1;
            tshift = wallA ? INFF : tv;

            if (naA == 0) {                    // A window 0 (head), B off
                up_prev = (lane == 0 && sig == 0) ? 0.0f : INFF;
                Q[0] = wp[0];              Q[1] = wp[(size_t)S];
                Q[2] = wp[(size_t)2 * S];  Q[3] = wp[(size_t)3 * S];
                WINBODY(P_AHEAD)
            } else if (naA == 1) {             // A on, B off
                WINBODY(P_AON)
            } else if (naA == 2) {             // A on, B window 0 (head)
                up_prev = is32 ? INFF : up_prev;   // reseed B's stream chain
                Q[0] = wp[0];              Q[1] = wp[(size_t)S];
                Q[2] = wp[(size_t)2 * S];  Q[3] = wp[(size_t)3 * S];
                WINBODY(P_BHEAD)
            } else if (naA <= 15) {            // both on — hot path (13 windows)
                WINBODY(P_NONE)
            } else if (naA == 16) {            // A window 16 (tail), B on
                WINBODY(P_ATAIL)
            } else if (naA == 17) {            // A done, B on
                WINBODY(P_BON)
            } else {                           // A done, B window 16 (tail)
                WINBODY(P_BTAIL)
            }

            // publish this window's boundary block + previous window's lasts
            ringbuf[n & 1][sig][lane] = tacc;
            if (isbot) ringbuf[n & 1][sig][64 + h] = eS;
            eS = r;                            // lanes 31/63: window-last value
        }
        __syncthreads();
    }
#undef P_BTAIL
#undef P_BON
#undef P_ATAIL
#undef P_BHEAD
#undef P_AON
#undef P_AHEAD
#undef P_NONE
#undef WINBODY
#undef GIT
#undef STEP

    // R[511][511]: pair 7 half B (strip 15), lane 63 = row 511, j=511
    if (tid == 511) out[b] = r;
}

// ---------------------------------------------------------------------------
extern "C" void kernel_launch(void* const* d_in, const int* in_sizes, int n_in,
                              void* d_out, int out_size, void* d_ws, size_t ws_size,
                              hipStream_t stream)
{
    const float* X = (const float*)d_in[0];
    const float* Y = (const float*)d_in[1];
    float* out = (float*)d_out;
    float* Dd  = (float*)d_ws;   // 32 * 256*512*4 floats = 64 MiB

    dim3 g1(S / 64, S / 64, BATCH);
    pairdist_kernel<<<g1, 256, 0, stream>>>(X, Y, Dd);

    softdtw_dp_hw<<<BATCH, 512, 0, stream>>>(Dd, out);
}